// Round 11
// baseline (280.445 us; speedup 1.0000x reference)
//
#include <hip/hip_runtime.h>
#include <math.h>

#define N_NODES 100000
#define N_EDGES 1600000
#define C_DIM 40
#define NGROUPS 6250                      // 100000 / 16 exactly

#define BSZ 256                           // nodes per bucket
#define NB  ((N_NODES + BSZ - 1) / BSZ)   // 391
#define EB  4096                          // edges per hist/scatter block
#define NBE ((N_EDGES + EB - 1) / EB)     // 391

// ---------------- workspace layout (4-byte units) ----------------
#define OFF_DINV 0                        // float[100000]
#define OFF_BB   100000                   // int[NB+1]
#define OFF_CS   100392                   // int[NB] column sums
#define OFF_ROW  100800                   // int[N+1]
#define OFF_H    200802                   // int[NBE*NB]
#define OFF_REC2 353684                   // int2[E] sorted records (even -> 8B aligned)
#define OFF_H1P  3553684                  // ushort[N*64] bf16 h1'; unsorted rec aliases here
#define OFF_H2P  6753684                  // ushort[N*64] bf16 h2' (128B padded rows)
#define OFF_R1P  9953684                  // ushort[N*64] bf16 relu(agg1+b1)

typedef float floatx4 __attribute__((ext_vector_type(4)));
typedef short shortx8 __attribute__((ext_vector_type(8)));

__device__ inline unsigned short f2bf(float f) {
    unsigned int u = __float_as_uint(f);
    u += 0x7FFF + ((u >> 16) & 1);        // round to nearest even
    return (unsigned short)(u >> 16);
}
__device__ inline float bf2f(unsigned short h) {
    return __uint_as_float(((unsigned int)h) << 16);
}
__device__ inline float bflo(unsigned int u) { return __uint_as_float(u << 16); }
__device__ inline float bfhi(unsigned int u) { return __uint_as_float(u & 0xFFFF0000u); }

// ---------- per-block bucket histogram: H[b][j] + global column sums ----------
__global__ __launch_bounds__(512) void k_hist2d(const int* __restrict__ ei,
                                                int* __restrict__ H,
                                                int* __restrict__ colsum) {
    __shared__ int bins[NB];
    int t = threadIdx.x, b = blockIdx.x;
    for (int i = t; i < NB; i += 512) bins[i] = 0;
    __syncthreads();
    int base = b * EB;
    for (int i = t; i < EB; i += 512) {
        int e = base + i;
        if (e < N_EDGES) atomicAdd(&bins[ei[N_EDGES + e] >> 8], 1);
    }
    __syncthreads();
    for (int i = t; i < NB; i += 512) {
        int c = bins[i];
        H[b * NB + i] = c;
        if (c) atomicAdd(&colsum[i], c);
    }
}

// ---------- column scan (self-computes bucketBase[j] from colsum) ----------
__global__ __launch_bounds__(512) void k_colscan(int* __restrict__ H,
                                                 const int* __restrict__ colsum,
                                                 int* __restrict__ bucketBase,
                                                 int* __restrict__ rowStart) {
    __shared__ int sd[512];
    __shared__ int sbase;
    int t = threadIdx.x, j = blockIdx.x;
    int p = 0;
    for (int i = t; i < j; i += 512) p += colsum[i];
    sd[t] = p;
    __syncthreads();
    for (int off = 256; off > 0; off >>= 1) {
        if (t < off) sd[t] += sd[t + off];
        __syncthreads();
    }
    if (t == 0) sbase = sd[0];
    __syncthreads();
    int base = sbase;
    if (t == 0) {
        bucketBase[j] = base;
        if (j == NB - 1) { bucketBase[NB] = base + colsum[j]; rowStart[N_NODES] = N_EDGES; }
    }
    __syncthreads();
    int val = (t < NBE) ? H[t * NB + j] : 0;
    sd[t] = val;
    __syncthreads();
    for (int off = 1; off < 512; off <<= 1) {
        int v = (t >= off) ? sd[t - off] : 0;
        __syncthreads();
        sd[t] += v;
        __syncthreads();
    }
    if (t < NBE) H[t * NB + j] = base + sd[t] - val;
}

// ---------- scatter into bucket regions (LDS cursors, no global atomics) ----------
__global__ __launch_bounds__(512) void k_scatter(const int* __restrict__ ei,
                                                 const float* __restrict__ w,
                                                 const int* __restrict__ blockBase,
                                                 int2* __restrict__ rec) {
    __shared__ int bases[NB];
    __shared__ int cur[NB];
    int t = threadIdx.x, b = blockIdx.x;
    for (int i = t; i < NB; i += 512) { bases[i] = blockBase[b * NB + i]; cur[i] = 0; }
    __syncthreads();
    int base = b * EB;
    for (int i = t; i < EB; i += 512) {
        int e = base + i;
        if (e < N_EDGES) {
            int s = ei[e], d = ei[N_EDGES + e];
            float wv = w[e];
            int bin = d >> 8;
            int pos = bases[bin] + atomicAdd(&cur[bin], 1);
            rec[pos] = make_int2(s | ((d & 255) << 17), __float_as_int(wv));
        }
    }
}

// ---------- per-bucket counting sort; payload = w*dinv[dst]; x = src byte-offset ----------
__global__ __launch_bounds__(512) void k_bsort(const int* __restrict__ bucketBase,
                                               const int2* __restrict__ rec,
                                               int2* __restrict__ rec2,
                                               float* __restrict__ dinv,
                                               int* __restrict__ rowStart) {
    __shared__ int   cnt[256];
    __shared__ float wsum[256];
    __shared__ int   cur[256];
    __shared__ int   sd[512];
    int t = threadIdx.x, b = blockIdx.x;
    if (t < 256) { cnt[t] = 0; wsum[t] = 0.f; }
    __syncthreads();
    int r0 = bucketBase[b], r1 = bucketBase[b + 1];
    for (int i = r0 + t; i < r1; i += 512) {
        int2 rv = rec[i];
        int l = (rv.x >> 17) & 255;
        atomicAdd(&cnt[l], 1);
        atomicAdd(&wsum[l], __int_as_float(rv.y));
    }
    __syncthreads();
    int val = (t < 256) ? cnt[t] : 0;
    sd[t] = val;
    __syncthreads();
    for (int off = 1; off < 512; off <<= 1) {
        int v = (t >= off) ? sd[t - off] : 0;
        __syncthreads();
        sd[t] += v;
        __syncthreads();
    }
    float dloc = 0.f;
    if (t < 256) {
        int excl = sd[t] - val;
        cur[t] = excl;
        int node = b * BSZ + t;
        dloc = rsqrtf(1.f + wsum[t]);
        if (node < N_NODES) {
            rowStart[node] = r0 + excl;
            dinv[node] = dloc;
        }
    }
    __syncthreads();
    if (t < 256) wsum[t] = dloc;
    __syncthreads();
    for (int i = r0 + t; i < r1; i += 512) {
        int2 rv = rec[i];
        int l = (rv.x >> 17) & 255;
        float cpart = __int_as_float(rv.y) * wsum[l];   // w * dinv[dst]
        int pos = r0 + atomicAdd(&cur[l], 1);
        rec2[pos] = make_int2((rv.x & 0x1FFFF) << 7, __float_as_int(cpart));  // src*128B
    }
}

// ---------- h1' = (x @ W1) * dinv[row] via MFMA, stored bf16 ----------
__global__ __launch_bounds__(256) void k_mm1(const float* __restrict__ x,
                                             const float* __restrict__ W1,
                                             const float* __restrict__ dinv,
                                             unsigned short* __restrict__ h1p) {
    int t = threadIdx.x, lane = t & 63, wv = t >> 6;
    int m = lane & 15, quad = lane >> 4;
    int wid = blockIdx.x * 4 + wv, nw = gridDim.x * 4;
    shortx8 B[2][4];
#pragma unroll
    for (int kc = 0; kc < 2; ++kc)
#pragma unroll
        for (int tt = 0; tt < 4; ++tt)
#pragma unroll
            for (int j = 0; j < 8; ++j) {
                int k = kc * 32 + quad * 8 + j;
                B[kc][tt][j] = (short)f2bf(W1[k * 64 + tt * 16 + m]);
            }
    for (int g = wid; g < NGROUPS; g += nw) {
        int n0 = g * 16;
        const float* xr = x + (long)(n0 + m) * 64 + quad * 8;
        floatx4 xa = ((const floatx4*)xr)[0];
        floatx4 xb = ((const floatx4*)(xr + 4))[0];
        floatx4 xc = ((const floatx4*)(xr + 32))[0];
        floatx4 xd = ((const floatx4*)(xr + 36))[0];
        shortx8 A0, A1;
#pragma unroll
        for (int j = 0; j < 4; ++j) {
            A0[j] = (short)f2bf(xa[j]);
            A0[4 + j] = (short)f2bf(xb[j]);
            A1[j] = (short)f2bf(xc[j]);
            A1[4 + j] = (short)f2bf(xd[j]);
        }
        floatx4 acc[4];
#pragma unroll
        for (int tt = 0; tt < 4; ++tt) {
            acc[tt] = (floatx4){0.f, 0.f, 0.f, 0.f};
            acc[tt] = __builtin_amdgcn_mfma_f32_16x16x32_bf16(A0, B[0][tt], acc[tt], 0, 0, 0);
            acc[tt] = __builtin_amdgcn_mfma_f32_16x16x32_bf16(A1, B[1][tt], acc[tt], 0, 0, 0);
        }
        floatx4 dv = ((const floatx4*)(dinv + n0 + quad * 4))[0];
#pragma unroll
        for (int reg = 0; reg < 4; ++reg) {
            int node = n0 + quad * 4 + reg;
            float d = dv[reg];
#pragma unroll
            for (int tt = 0; tt < 4; ++tt)
                h1p[(long)node * 64 + tt * 16 + m] = f2bf(acc[tt][reg] * d);
        }
    }
}

// ---------- agg1: 8 edge-slots x 8 lanes, dwordx4 (8 cols) per lane ----------
// Epilogue fuses relu(acc+b1) -> bf16 r1p (mm2 prologue moved here).
__global__ __launch_bounds__(256) void k_agg1(const int* __restrict__ rowStart,
                                              const int2* __restrict__ rec2,
                                              const float* __restrict__ dinv,
                                              const unsigned short* __restrict__ h1p,
                                              const float* __restrict__ b1,
                                              unsigned short* __restrict__ r1p) {
    __shared__ int2 cache[4][64];
    int t = threadIdx.x, lane = t & 63, wv = t >> 6;
    int node = blockIdx.x * 4 + wv;
    if (node >= N_NODES) return;
    int2* wc = cache[wv];
    wc[lane] = make_int2(0, 0);
    const char* hb = (const char*)h1p;
    int eslot = lane >> 3;                // 0..7
    int c = lane & 7;                     // 16B chunk -> cols 8c..8c+7
    int lo = c << 4;
    float dn = dinv[node];
    float a0 = 0, a1 = 0, a2 = 0, a3 = 0, a4 = 0, a5 = 0, a6 = 0, a7 = 0;
    float g0 = 0, g1 = 0, g2 = 0, g3 = 0, g4 = 0, g5 = 0, g6 = 0, g7 = 0;
    if (eslot == 0) {                     // self loop: h1'*dinv = h1*dinv^2
        uint4 u = *(const uint4*)(hb + ((long)node << 7) + lo);
        a0 = bflo(u.x) * dn; a1 = bfhi(u.x) * dn;
        a2 = bflo(u.y) * dn; a3 = bfhi(u.y) * dn;
        a4 = bflo(u.z) * dn; a5 = bfhi(u.z) * dn;
        a6 = bflo(u.w) * dn; a7 = bfhi(u.w) * dn;
    }
    int s0 = rowStart[node], s1 = rowStart[node + 1];
    for (int base = s0; base < s1; base += 64) {
        int idx = base + lane;
        if (idx < s1) wc[lane] = rec2[idx];
        __builtin_amdgcn_wave_barrier();
        int cnt = min(64, s1 - base);
        int j = 0;
        for (; j + 15 < cnt; j += 16) {
            int2 eA = wc[j + eslot];
            int2 eB = wc[j + 8 + eslot];
            uint4 uA = *(const uint4*)(hb + eA.x + lo);
            uint4 uB = *(const uint4*)(hb + eB.x + lo);
            float cA = __int_as_float(eA.y), cB = __int_as_float(eB.y);
            a0 = fmaf(bflo(uA.x), cA, a0); a1 = fmaf(bfhi(uA.x), cA, a1);
            a2 = fmaf(bflo(uA.y), cA, a2); a3 = fmaf(bfhi(uA.y), cA, a3);
            a4 = fmaf(bflo(uA.z), cA, a4); a5 = fmaf(bfhi(uA.z), cA, a5);
            a6 = fmaf(bflo(uA.w), cA, a6); a7 = fmaf(bfhi(uA.w), cA, a7);
            g0 = fmaf(bflo(uB.x), cB, g0); g1 = fmaf(bfhi(uB.x), cB, g1);
            g2 = fmaf(bflo(uB.y), cB, g2); g3 = fmaf(bfhi(uB.y), cB, g3);
            g4 = fmaf(bflo(uB.z), cB, g4); g5 = fmaf(bfhi(uB.z), cB, g5);
            g6 = fmaf(bflo(uB.w), cB, g6); g7 = fmaf(bfhi(uB.w), cB, g7);
        }
        for (; j < cnt; j += 8) {
            int jj = j + eslot;
            bool valid = jj < cnt;
            int2 e = wc[valid ? jj : j];
            float cc = valid ? __int_as_float(e.y) : 0.f;
            uint4 u = *(const uint4*)(hb + e.x + lo);
            a0 = fmaf(bflo(u.x), cc, a0); a1 = fmaf(bfhi(u.x), cc, a1);
            a2 = fmaf(bflo(u.y), cc, a2); a3 = fmaf(bfhi(u.y), cc, a3);
            a4 = fmaf(bflo(u.z), cc, a4); a5 = fmaf(bfhi(u.z), cc, a5);
            a6 = fmaf(bflo(u.w), cc, a6); a7 = fmaf(bfhi(u.w), cc, a7);
        }
        __builtin_amdgcn_wave_barrier();
    }
    a0 += g0; a1 += g1; a2 += g2; a3 += g3;
    a4 += g4; a5 += g5; a6 += g6; a7 += g7;
#define RED(v) v += __shfl_xor(v, 8, 64); v += __shfl_xor(v, 16, 64); v += __shfl_xor(v, 32, 64)
    RED(a0); RED(a1); RED(a2); RED(a3); RED(a4); RED(a5); RED(a6); RED(a7);
#undef RED
    if (eslot == 0) {
        floatx4 bva = ((const floatx4*)(b1 + (c << 3)))[0];
        floatx4 bvb = ((const floatx4*)(b1 + (c << 3) + 4))[0];
        shortx8 v;
        v[0] = (short)f2bf(fmaxf(a0 + bva[0], 0.f));
        v[1] = (short)f2bf(fmaxf(a1 + bva[1], 0.f));
        v[2] = (short)f2bf(fmaxf(a2 + bva[2], 0.f));
        v[3] = (short)f2bf(fmaxf(a3 + bva[3], 0.f));
        v[4] = (short)f2bf(fmaxf(a4 + bvb[0], 0.f));
        v[5] = (short)f2bf(fmaxf(a5 + bvb[1], 0.f));
        v[6] = (short)f2bf(fmaxf(a6 + bvb[2], 0.f));
        v[7] = (short)f2bf(fmaxf(a7 + bvb[3], 0.f));
        *(shortx8*)(r1p + ((long)node << 6) + (c << 3)) = v;
    }
}

// ---------- h2' = (r1' @ W2) * dinv via MFMA (bf16 in), 128B-padded rows ----------
__global__ __launch_bounds__(256) void k_mm2(const unsigned short* __restrict__ r1p,
                                             const float* __restrict__ W2,
                                             const float* __restrict__ dinv,
                                             unsigned short* __restrict__ h2p) {
    int t = threadIdx.x, lane = t & 63, wv = t >> 6;
    int m = lane & 15, quad = lane >> 4;
    int wid = blockIdx.x * 4 + wv, nw = gridDim.x * 4;
    shortx8 B[2][3];
#pragma unroll
    for (int kc = 0; kc < 2; ++kc)
#pragma unroll
        for (int tt = 0; tt < 3; ++tt) {
            int n = tt * 16 + m;
#pragma unroll
            for (int j = 0; j < 8; ++j) {
                int k = kc * 32 + quad * 8 + j;
                B[kc][tt][j] = (n < C_DIM) ? (short)f2bf(W2[k * C_DIM + n]) : (short)0;
            }
        }
    for (int g = wid; g < NGROUPS; g += nw) {
        int n0 = g * 16;
        const unsigned short* rr = r1p + ((long)(n0 + m) << 6) + quad * 8;
        shortx8 A0 = *(const shortx8*)rr;
        shortx8 A1 = *(const shortx8*)(rr + 32);
        floatx4 acc[3];
#pragma unroll
        for (int tt = 0; tt < 3; ++tt) {
            acc[tt] = (floatx4){0.f, 0.f, 0.f, 0.f};
            acc[tt] = __builtin_amdgcn_mfma_f32_16x16x32_bf16(A0, B[0][tt], acc[tt], 0, 0, 0);
            acc[tt] = __builtin_amdgcn_mfma_f32_16x16x32_bf16(A1, B[1][tt], acc[tt], 0, 0, 0);
        }
        floatx4 dv = ((const floatx4*)(dinv + n0 + quad * 4))[0];
#pragma unroll
        for (int reg = 0; reg < 4; ++reg) {
            int node = n0 + quad * 4 + reg;
            float d = dv[reg];
#pragma unroll
            for (int tt = 0; tt < 3; ++tt) {
                int col = tt * 16 + m;
                if (col < C_DIM)
                    h2p[((long)node << 6) + col] = f2bf(acc[tt][reg] * d);
            }
        }
    }
}

// ---------- agg2: 6 edge-slots x 10 lanes, dwordx2 (4 cols) per lane + softmax ----------
__global__ __launch_bounds__(256) void k_agg2(const int* __restrict__ rowStart,
                                              const int2* __restrict__ rec2,
                                              const float* __restrict__ dinv,
                                              const unsigned short* __restrict__ h2p,
                                              const float* __restrict__ b2,
                                              float* __restrict__ out) {
    __shared__ int2 cache[4][64];
    int t = threadIdx.x, lane = t & 63, wv = t >> 6;
    int node = blockIdx.x * 4 + wv;
    if (node >= N_NODES) return;
    int2* wc = cache[wv];
    wc[lane] = make_int2(0, 0);
    const char* hb = (const char*)h2p;
    int eslot = lane / 10;                // 0..6 (lanes 60..63 -> 6, inactive)
    int c = lane - eslot * 10;            // 0..9 -> cols 4c..4c+3
    bool elane = eslot < 6;
    int lo = c << 3;
    float dn = dinv[node];
    float a0 = 0, a1 = 0, a2 = 0, a3 = 0;
    float g0 = 0, g1 = 0, g2 = 0, g3 = 0;
    if (eslot == 0) {                     // self loop
        uint2 u = *(const uint2*)(hb + ((long)node << 7) + lo);
        a0 = bflo(u.x) * dn; a1 = bfhi(u.x) * dn;
        a2 = bflo(u.y) * dn; a3 = bfhi(u.y) * dn;
    }
    int s0 = rowStart[node], s1 = rowStart[node + 1];
    for (int base = s0; base < s1; base += 64) {
        int idx = base + lane;
        if (idx < s1) wc[lane] = rec2[idx];
        __builtin_amdgcn_wave_barrier();
        int cnt = min(64, s1 - base);
        int j = 0;
        for (; j + 11 < cnt; j += 12) {
            int2 eA = wc[j + eslot];
            int2 eB = wc[j + 6 + eslot];
            uint2 uA = *(const uint2*)(hb + eA.x + lo);
            uint2 uB = *(const uint2*)(hb + eB.x + lo);
            float cA = elane ? __int_as_float(eA.y) : 0.f;
            float cB = elane ? __int_as_float(eB.y) : 0.f;
            a0 = fmaf(bflo(uA.x), cA, a0); a1 = fmaf(bfhi(uA.x), cA, a1);
            a2 = fmaf(bflo(uA.y), cA, a2); a3 = fmaf(bfhi(uA.y), cA, a3);
            g0 = fmaf(bflo(uB.x), cB, g0); g1 = fmaf(bfhi(uB.x), cB, g1);
            g2 = fmaf(bflo(uB.y), cB, g2); g3 = fmaf(bfhi(uB.y), cB, g3);
        }
        for (; j < cnt; j += 6) {
            int jj = j + eslot;
            bool valid = elane && (jj < cnt);
            int2 e = wc[valid ? jj : j];
            float cc = valid ? __int_as_float(e.y) : 0.f;
            uint2 u = *(const uint2*)(hb + e.x + lo);
            a0 = fmaf(bflo(u.x), cc, a0); a1 = fmaf(bfhi(u.x), cc, a1);
            a2 = fmaf(bflo(u.y), cc, a2); a3 = fmaf(bfhi(u.y), cc, a3);
        }
        __builtin_amdgcn_wave_barrier();
    }
    a0 += g0; a1 += g1; a2 += g2; a3 += g3;
    // cross-slot reduce: final(c) = sum over lanes c+10k, k=0..5
#define RED6(v) v += __shfl(v, (lane + 30) & 63, 64); \
                v += __shfl(v, (lane + 10) & 63, 64) + __shfl(v, (lane + 20) & 63, 64)
    RED6(a0); RED6(a1); RED6(a2); RED6(a3);
#undef RED6
    bool act = lane < 10;
    floatx4 bb = act ? ((const floatx4*)(b2 + (c << 2)))[0] : (floatx4){0, 0, 0, 0};
    float v0 = act ? a0 + bb[0] : -INFINITY;
    float v1 = act ? a1 + bb[1] : -INFINITY;
    float v2 = act ? a2 + bb[2] : -INFINITY;
    float v3 = act ? a3 + bb[3] : -INFINITY;
    float m = fmaxf(fmaxf(v0, v1), fmaxf(v2, v3));
#pragma unroll
    for (int off = 32; off; off >>= 1) m = fmaxf(m, __shfl_xor(m, off, 64));
    float s = act ? (expf(v0 - m) + expf(v1 - m)) + (expf(v2 - m) + expf(v3 - m)) : 0.f;
#pragma unroll
    for (int off = 32; off; off >>= 1) s += __shfl_xor(s, off, 64);
    float ls = m + logf(s);
    if (act) {
        *(float4*)(out + (long)node * C_DIM + (c << 2)) =
            make_float4(v0 - ls, v1 - ls, v2 - ls, v3 - ls);
    }
}

extern "C" void kernel_launch(void* const* d_in, const int* in_sizes, int n_in,
                              void* d_out, int out_size, void* d_ws, size_t ws_size,
                              hipStream_t stream) {
    const float* x  = (const float*)d_in[0];
    const int*   ei = (const int*)d_in[1];
    const float* w  = (const float*)d_in[2];
    const float* W1 = (const float*)d_in[3];
    const float* b1 = (const float*)d_in[4];
    const float* W2 = (const float*)d_in[5];
    const float* b2 = (const float*)d_in[6];
    float* out = (float*)d_out;

    float* wsf = (float*)d_ws;
    int*   wsi = (int*)d_ws;
    float* dinv       = wsf + OFF_DINV;
    int*   bucketBase = wsi + OFF_BB;
    int*   colsum     = wsi + OFF_CS;
    int*   rowStart   = wsi + OFF_ROW;
    int*   H          = wsi + OFF_H;
    int2*  rec2       = (int2*)(wsi + OFF_REC2);
    int2*  rec        = (int2*)(wsi + OFF_H1P);              // dead before h1p written
    unsigned short* h1p = (unsigned short*)(wsi + OFF_H1P);
    unsigned short* h2p = (unsigned short*)(wsi + OFF_H2P);
    unsigned short* r1p = (unsigned short*)(wsi + OFF_R1P);

    // CSR build — zero global atomics except 391-bin colsum
    hipMemsetAsync(colsum, 0, NB * sizeof(int), stream);
    k_hist2d<<<NBE, 512, 0, stream>>>(ei, H, colsum);
    k_colscan<<<NB, 512, 0, stream>>>(H, colsum, bucketBase, rowStart);
    k_scatter<<<NBE, 512, 0, stream>>>(ei, w, H, rec);
    k_bsort<<<NB, 512, 0, stream>>>(bucketBase, rec, rec2, dinv, rowStart);

    // layer 1 (MFMA matmul + gather-aggregate w/ fused relu+bias epilogue)
    k_mm1<<<512, 256, 0, stream>>>(x, W1, dinv, h1p);
    k_agg1<<<(N_NODES + 3) / 4, 256, 0, stream>>>(rowStart, rec2, dinv, h1p, b1, r1p);

    // layer 2 (MFMA matmul + gather-aggregate w/ fused bias/log-softmax)
    k_mm2<<<512, 256, 0, stream>>>(r1p, W2, dinv, h2p);
    k_agg2<<<(N_NODES + 3) / 4, 256, 0, stream>>>(rowStart, rec2, dinv, h2p, b2, out);
}